// Round 5
// baseline (130.602 us; speedup 1.0000x reference)
//
#include <hip/hip_runtime.h>

// CombinedLoss = 0.7 * class-weighted Dice + 0.3 * Sobel-boundary BCE
// [B=8,C=4,H=512,W=512] fp32. Binary boundary BCE == 100 * mismatch-rate.
// Register-streaming: one wave = one 512-col row strip (8 cols/lane), 4 output
// rows/wave, 5-slot row window with halos resolved AT LOAD TIME:
//   probs: 10 floats/slot (8 own + 2 shuffled lane halos)
//   targets: 10-bit mask/slot (binary -> exact integer Sobel, gx!=0 || gy!=0)
// No LDS tiles, no compute-phase shuffles. VGPR target <=128 (4 waves/SIMD).

#define H_ 512
#define W_ 512
#define NIMG 32
#define NPIXF 8388608.0f
#define R_ 4
#define NBLK 1024   // 32 img * 128 segs / 4 waves-per-block

__device__ __forceinline__ float sigf(float x) {
    return __builtin_amdgcn_rcpf(1.f + __expf(-x));
}

__launch_bounds__(256, 4)
__global__ void fused_loss_kernel(const float* __restrict__ logits,
                                  const float* __restrict__ targets,
                                  float4* __restrict__ part) {
    const int tid  = threadIdx.x;
    const int wid  = tid >> 6, lane = tid & 63;
    const int bx   = blockIdx.x;
    const int img  = bx >> 5;                  // 32 blocks per image
    const int seg  = ((bx & 31) << 2) | wid;   // 128 segments per image
    const int y0   = seg << 2;

    const float* Lp = logits  + (size_t)img * (H_ * W_) + (lane << 3);
    const float* Tp = targets + (size_t)img * (H_ * W_) + (lane << 3);

    float p[5][10];        // [slot][0]=left halo, [1..8]=own cols, [9]=right halo
    unsigned int win[5];   // bit0=left halo, bits1..8=own cols, bit9=right halo

    auto loadrow = [&](int gy, int s) {
        if ((unsigned)gy < (unsigned)H_) {
            const float4 va = *(const float4*)(Lp + gy * W_);
            const float4 vb = *(const float4*)(Lp + gy * W_ + 4);
            const float4 vc = *(const float4*)(Tp + gy * W_);
            const float4 vd = *(const float4*)(Tp + gy * W_ + 4);
            p[s][1] = sigf(va.x); p[s][2] = sigf(va.y);
            p[s][3] = sigf(va.z); p[s][4] = sigf(va.w);
            p[s][5] = sigf(vb.x); p[s][6] = sigf(vb.y);
            p[s][7] = sigf(vb.z); p[s][8] = sigf(vb.w);
            unsigned int m =  (vc.x > 0.5f ? 1u : 0u)       | (vc.y > 0.5f ? 2u : 0u)
                           | (vc.z > 0.5f ? 4u : 0u)        | (vc.w > 0.5f ? 8u : 0u)
                           | (vd.x > 0.5f ? 16u : 0u)       | (vd.y > 0.5f ? 32u : 0u)
                           | (vd.z > 0.5f ? 64u : 0u)       | (vd.w > 0.5f ? 128u : 0u);
            // lane halos (resolved here, not in compute phase)
            float pl = __shfl_up(p[s][8], 1, 64);
            float pr = __shfl_down(p[s][1], 1, 64);
            unsigned int ml = __shfl_up(m, 1, 64);
            unsigned int mr = __shfl_down(m, 1, 64);
            if (lane == 0)  { pl = 0.f; ml = 0u; }
            if (lane == 63) { pr = 0.f; mr = 0u; }
            p[s][0] = pl; p[s][9] = pr;
            win[s] = (m << 1) | ((ml >> 7) & 1u) | ((mr & 1u) << 9);
        } else {
            #pragma unroll
            for (int k = 0; k < 10; ++k) p[s][k] = 0.f;
            win[s] = 0u;
        }
    };

    loadrow(y0 - 1, 0);
    loadrow(y0,     1);
    loadrow(y0 + 1, 2);
    loadrow(y0 + 2, 3);

    float li = 0.f, lp = 0.f;
    int mi = 0, tcnt = 0;

    #pragma unroll
    for (int i = 0; i < R_; ++i) {
        if (i < 2) loadrow(y0 + 3 + i, (4 + i) % 5);   // depth-2 prefetch
        const int sA = i % 5, sB = (i + 1) % 5, sC = (i + 2) % 5;

        // probs: separable column sums over the 10-wide haloed row
        float Tc[10], Sc[10];
        #pragma unroll
        for (int j = 0; j < 10; ++j) {
            Tc[j] = (p[sA][j] + p[sC][j]) + 2.f * p[sB][j];
            Sc[j] = p[sC][j] - p[sA][j];
        }
        // targets: exact integer column sums from bit window
        const unsigned int wA = win[sA], wB = win[sB], wC = win[sC];
        int Tt[10], St[10];
        #pragma unroll
        for (int j = 0; j < 10; ++j) {
            const int a = (int)((wA >> j) & 1u);
            const int b = (int)((wB >> j) & 1u);
            const int c = (int)((wC >> j) & 1u);
            Tt[j] = a + 2 * b + c;
            St[j] = c - a;
        }

        #pragma unroll
        for (int k = 0; k < 8; ++k) {
            const float gx = Tc[k + 2] - Tc[k];
            const float gy = (Sc[k] + Sc[k + 2]) + 2.f * Sc[k + 1];
            const int pb = (gx * gx + gy * gy) > 0.25f;

            const int hx = Tt[k + 2] - Tt[k];
            const int hy = (St[k] + St[k + 2]) + 2 * St[k + 1];
            const int tb = ((hx | hy) != 0) ? 1 : 0;   // gx!=0 || gy!=0 (exact)

            mi += pb ^ tb;
            const float pv = p[sB][k + 1];
            lp += pv;
            if ((wB >> (k + 1)) & 1u) li += pv;
        }
        tcnt += __popc(wB & 0x1FEu);   // own-pixel target count for this row
    }
    float lt = (float)tcnt;
    float lm = (float)mi;

    #pragma unroll
    for (int off = 32; off > 0; off >>= 1) {
        li += __shfl_down(li, off, 64);
        lp += __shfl_down(lp, off, 64);
        lt += __shfl_down(lt, off, 64);
        lm += __shfl_down(lm, off, 64);
    }
    __shared__ float red[4][4];
    if (lane == 0) { red[wid][0] = li; red[wid][1] = lp; red[wid][2] = lt; red[wid][3] = lm; }
    __syncthreads();
    if (tid == 0) {
        float a = 0.f, b = 0.f, c = 0.f, d = 0.f;
        #pragma unroll
        for (int w = 0; w < 4; ++w) {
            a += red[w][0]; b += red[w][1]; c += red[w][2]; d += red[w][3];
        }
        part[bx] = make_float4(a, b, c, d);
    }
}

__global__ void finalize_kernel(const float4* __restrict__ part,
                                const float* __restrict__ cw,
                                float* __restrict__ out) {
    __shared__ float s_i[NIMG], s_p[NIMG], s_t[NIMG], s_m[NIMG];
    const int tid = threadIdx.x;           // 1024 threads, one per block-partial
    float4 v = part[tid];
    float vi = v.x, vp = v.y, vt = v.z, vm = v.w;
    #pragma unroll
    for (int off = 16; off > 0; off >>= 1) {   // 32 partials per image, segmented
        vi += __shfl_down(vi, off, 32);
        vp += __shfl_down(vp, off, 32);
        vt += __shfl_down(vt, off, 32);
        vm += __shfl_down(vm, off, 32);
    }
    if ((tid & 31) == 0) {
        const int img = tid >> 5;
        s_i[img] = vi; s_p[img] = vp; s_t[img] = vt; s_m[img] = vm;
    }
    __syncthreads();
    if (tid == 0) {
        float mm = 0.f;
        for (int i = 0; i < NIMG; ++i) mm += s_m[i];
        float wsum = 0.f, dl = 0.f;
        for (int c = 0; c < 4; ++c) {
            float md = 0.f;
            for (int b = 0; b < 8; ++b) {
                const int id = b * 4 + c;
                md += (2.f * s_i[id] + 1.f) / (s_p[id] + s_t[id] + 1.f);
            }
            md *= 0.125f;
            dl += cw[c] * (1.f - md);
            wsum += cw[c];
        }
        out[0] = 0.7f * (dl / wsum) + 0.3f * (100.f * mm / NPIXF);
    }
}

extern "C" void kernel_launch(void* const* d_in, const int* in_sizes, int n_in,
                              void* d_out, int out_size, void* d_ws, size_t ws_size,
                              hipStream_t stream) {
    const float* logits  = (const float*)d_in[0];
    const float* targets = (const float*)d_in[1];
    const float* cw      = (const float*)d_in[2];
    float* out = (float*)d_out;
    float4* part = (float4*)d_ws;   // NBLK * 16 B = 16 KB

    fused_loss_kernel<<<NBLK, 256, 0, stream>>>(logits, targets, part);
    finalize_kernel<<<1, NBLK, 0, stream>>>(part, cw, out);
}

// Round 6
// 105.148 us; speedup vs baseline: 1.2421x; 1.2421x over previous
//
#include <hip/hip_runtime.h>

// CombinedLoss = 0.7 * class-weighted Dice + 0.3 * Sobel-boundary BCE
// [B=8,C=4,H=512,W=512] fp32. Binary boundary BCE == 100 * mismatch-rate.
// One wave = one 512-col strip (8 cols/lane), 2 output rows/wave -> exactly 4
// input rows in four SEPARATELY NAMED register arrays (constant indices only —
// round-5's rotating p[i%5] window spilled to scratch: VGPR=64 + 49MB scratch
// writes). Targets as 10-bit masks (exact integer Sobel). Halos resolved at
// load time via 2 shuffles/row. No LDS tiles, no min-occupancy bound.

#define H_ 512
#define W_ 512
#define NIMG 32
#define NPIXF 8388608.0f
#define NBLK 2048   // 8192 waves: 32 img * 256 segs(2 rows each) / 4 waves-per-block

__device__ __forceinline__ float sigf(float x) {
    return __builtin_amdgcn_rcpf(1.f + __expf(-x));
}

__launch_bounds__(256)
__global__ void fused_loss_kernel(const float* __restrict__ logits,
                                  const float* __restrict__ targets,
                                  float4* __restrict__ part) {
    const int tid  = threadIdx.x;
    const int wid  = tid >> 6, lane = tid & 63;
    const int bx   = blockIdx.x;
    const int gwid = (bx << 2) | wid;       // 0..8191
    const int img  = gwid >> 8;             // 256 waves per image
    const int y0   = (gwid & 255) << 1;     // 2 rows per wave

    const float* Lp = logits  + (size_t)img * (H_ * W_) + (lane << 3);
    const float* Tp = targets + (size_t)img * (H_ * W_) + (lane << 3);

    // [0]=left halo, [1..8]=own cols, [9]=right halo
    float p0[10], p1[10], p2[10], p3[10];
    unsigned int w0, w1, w2, w3;

    auto loadrow = [&](int gy, float (&pr)[10], unsigned int& wr) {
        if ((unsigned)gy < (unsigned)H_) {   // wave-uniform branch: shuffles safe
            const float4 va = *(const float4*)(Lp + gy * W_);
            const float4 vb = *(const float4*)(Lp + gy * W_ + 4);
            const float4 vc = *(const float4*)(Tp + gy * W_);
            const float4 vd = *(const float4*)(Tp + gy * W_ + 4);
            pr[1] = sigf(va.x); pr[2] = sigf(va.y);
            pr[3] = sigf(va.z); pr[4] = sigf(va.w);
            pr[5] = sigf(vb.x); pr[6] = sigf(vb.y);
            pr[7] = sigf(vb.z); pr[8] = sigf(vb.w);
            unsigned int m =  (vc.x > 0.5f ? 1u : 0u)   | (vc.y > 0.5f ? 2u : 0u)
                           | (vc.z > 0.5f ? 4u : 0u)    | (vc.w > 0.5f ? 8u : 0u)
                           | (vd.x > 0.5f ? 16u : 0u)   | (vd.y > 0.5f ? 32u : 0u)
                           | (vd.z > 0.5f ? 64u : 0u)   | (vd.w > 0.5f ? 128u : 0u);
            float pl = __shfl_up(pr[8], 1, 64);
            float pr9 = __shfl_down(pr[1], 1, 64);
            unsigned int ml = __shfl_up(m, 1, 64);
            unsigned int mr = __shfl_down(m, 1, 64);
            if (lane == 0)  { pl = 0.f; ml = 0u; }
            if (lane == 63) { pr9 = 0.f; mr = 0u; }
            pr[0] = pl; pr[9] = pr9;
            wr = (m << 1) | ((ml >> 7) & 1u) | ((mr & 1u) << 9);
        } else {
            #pragma unroll
            for (int k = 0; k < 10; ++k) pr[k] = 0.f;
            wr = 0u;
        }
    };

    loadrow(y0 - 1, p0, w0);
    loadrow(y0,     p1, w1);
    loadrow(y0 + 1, p2, w2);
    loadrow(y0 + 2, p3, w3);

    float li = 0.f, lp = 0.f;
    int mi = 0;

    // ---- output row A: rows (p0,p1,p2), mask rows (w0,w1,w2) ----
    {
        float Tc[10], Sc[10];
        #pragma unroll
        for (int j = 0; j < 10; ++j) {
            Tc[j] = (p0[j] + p2[j]) + 2.f * p1[j];
            Sc[j] = p2[j] - p0[j];
        }
        #pragma unroll
        for (int k = 0; k < 8; ++k) {
            const float gx = Tc[k + 2] - Tc[k];
            const float gy = (Sc[k] + Sc[k + 2]) + 2.f * Sc[k + 1];
            const int pb = (gx * gx + gy * gy) > 0.25f;
            const int a0 = (int)((w0 >> k) & 7u);       // 3-bit neighborhoods
            const int a1 = (int)((w1 >> k) & 7u);
            const int a2 = (int)((w2 >> k) & 7u);
            // integer Sobel != 0 test on bits {k,k+1,k+2} of rows w0,w1,w2
            const int t3 = (a0 & 1) + 2 * (a1 & 1) + (a2 & 1);
            const int t5 = ((a0 >> 2) & 1) + 2 * ((a1 >> 2) & 1) + ((a2 >> 2) & 1);
            const int s3 = (a2 & 1) - (a0 & 1);
            const int s4 = ((a2 >> 1) & 1) - ((a0 >> 1) & 1);
            const int s5 = ((a2 >> 2) & 1) - ((a0 >> 2) & 1);
            const int tb = (((t5 - t3) | (s3 + 2 * s4 + s5)) != 0) ? 1 : 0;
            mi += pb ^ tb;
            const float pv = p1[k + 1];
            lp += pv;
            if ((w1 >> (k + 1)) & 1u) li += pv;
        }
    }
    // ---- output row B: rows (p1,p2,p3), mask rows (w1,w2,w3) ----
    {
        float Tc[10], Sc[10];
        #pragma unroll
        for (int j = 0; j < 10; ++j) {
            Tc[j] = (p1[j] + p3[j]) + 2.f * p2[j];
            Sc[j] = p3[j] - p1[j];
        }
        #pragma unroll
        for (int k = 0; k < 8; ++k) {
            const float gx = Tc[k + 2] - Tc[k];
            const float gy = (Sc[k] + Sc[k + 2]) + 2.f * Sc[k + 1];
            const int pb = (gx * gx + gy * gy) > 0.25f;
            const int a0 = (int)((w1 >> k) & 7u);
            const int a1 = (int)((w2 >> k) & 7u);
            const int a2 = (int)((w3 >> k) & 7u);
            const int t3 = (a0 & 1) + 2 * (a1 & 1) + (a2 & 1);
            const int t5 = ((a0 >> 2) & 1) + 2 * ((a1 >> 2) & 1) + ((a2 >> 2) & 1);
            const int s3 = (a2 & 1) - (a0 & 1);
            const int s4 = ((a2 >> 1) & 1) - ((a0 >> 1) & 1);
            const int s5 = ((a2 >> 2) & 1) - ((a0 >> 2) & 1);
            const int tb = (((t5 - t3) | (s3 + 2 * s4 + s5)) != 0) ? 1 : 0;
            mi += pb ^ tb;
            const float pv = p2[k + 1];
            lp += pv;
            if ((w2 >> (k + 1)) & 1u) li += pv;
        }
    }

    float lt = (float)(__popc(w1 & 0x1FEu) + __popc(w2 & 0x1FEu));
    float lm = (float)mi;

    #pragma unroll
    for (int off = 32; off > 0; off >>= 1) {
        li += __shfl_down(li, off, 64);
        lp += __shfl_down(lp, off, 64);
        lt += __shfl_down(lt, off, 64);
        lm += __shfl_down(lm, off, 64);
    }
    __shared__ float red[4][4];
    if (lane == 0) { red[wid][0] = li; red[wid][1] = lp; red[wid][2] = lt; red[wid][3] = lm; }
    __syncthreads();
    if (tid == 0) {
        float a = 0.f, b = 0.f, c = 0.f, d = 0.f;
        #pragma unroll
        for (int w = 0; w < 4; ++w) {
            a += red[w][0]; b += red[w][1]; c += red[w][2]; d += red[w][3];
        }
        part[bx] = make_float4(a, b, c, d);
    }
}

__global__ void finalize_kernel(const float4* __restrict__ part,
                                const float* __restrict__ cw,
                                float* __restrict__ out) {
    __shared__ float s_i[NIMG], s_p[NIMG], s_t[NIMG], s_m[NIMG];
    const int tid = threadIdx.x;   // 1024 threads; 2048 partials, 64 per image
    float4 a = part[2 * tid];
    float4 b = part[2 * tid + 1];  // adjacent pair -> same image (64 per image)
    float vi = a.x + b.x, vp = a.y + b.y, vt = a.z + b.z, vm = a.w + b.w;
    #pragma unroll
    for (int off = 16; off > 0; off >>= 1) {   // 32 pair-sums per image
        vi += __shfl_down(vi, off, 32);
        vp += __shfl_down(vp, off, 32);
        vt += __shfl_down(vt, off, 32);
        vm += __shfl_down(vm, off, 32);
    }
    if ((tid & 31) == 0) {
        const int img = tid >> 5;
        s_i[img] = vi; s_p[img] = vp; s_t[img] = vt; s_m[img] = vm;
    }
    __syncthreads();
    if (tid == 0) {
        float mm = 0.f;
        for (int i = 0; i < NIMG; ++i) mm += s_m[i];
        float wsum = 0.f, dl = 0.f;
        for (int c = 0; c < 4; ++c) {
            float md = 0.f;
            for (int b2 = 0; b2 < 8; ++b2) {
                const int id = b2 * 4 + c;
                md += (2.f * s_i[id] + 1.f) / (s_p[id] + s_t[id] + 1.f);
            }
            md *= 0.125f;
            dl += cw[c] * (1.f - md);
            wsum += cw[c];
        }
        out[0] = 0.7f * (dl / wsum) + 0.3f * (100.f * mm / NPIXF);
    }
}

extern "C" void kernel_launch(void* const* d_in, const int* in_sizes, int n_in,
                              void* d_out, int out_size, void* d_ws, size_t ws_size,
                              hipStream_t stream) {
    const float* logits  = (const float*)d_in[0];
    const float* targets = (const float*)d_in[1];
    const float* cw      = (const float*)d_in[2];
    float* out = (float*)d_out;
    float4* part = (float4*)d_ws;   // NBLK * 16 B = 32 KB

    fused_loss_kernel<<<NBLK, 256, 0, stream>>>(logits, targets, part);
    finalize_kernel<<<1, 1024, 0, stream>>>(part, cw, out);
}

// Round 7
// 104.102 us; speedup vs baseline: 1.2546x; 1.0100x over previous
//
#include <hip/hip_runtime.h>

// CombinedLoss = 0.7 * class-weighted Dice + 0.3 * Sobel-boundary BCE
// [B=8,C=4,H=512,W=512] fp32. Binary boundary BCE == 100 * mismatch-rate.
// One wave = one 512-col strip (8 cols/lane), 4 output rows/wave -> exactly 6
// input rows in six SEPARATELY NAMED register arrays (constant indices only;
// rotating/computed-index windows spill to scratch — round-5 lesson).
// Targets as 10-bit masks; target Sobel via per-row integer column sums
// (CSE across pixels, mirrors float path). Halos resolved at load time.
// No LDS tiles, no min-occupancy bound (let allocator pick VGPRs).

#define H_ 512
#define W_ 512
#define NIMG 32
#define NPIXF 8388608.0f
#define NBLK 1024   // 4096 waves: 32 img * 128 segs(4 rows each) / 4 waves-per-block

__device__ __forceinline__ float sigf(float x) {
    return __builtin_amdgcn_rcpf(1.f + __expf(-x));
}

__launch_bounds__(256)
__global__ void fused_loss_kernel(const float* __restrict__ logits,
                                  const float* __restrict__ targets,
                                  float4* __restrict__ part) {
    const int tid  = threadIdx.x;
    const int wid  = tid >> 6, lane = tid & 63;
    const int bx   = blockIdx.x;
    const int gwid = (bx << 2) | wid;       // 0..4095
    const int img  = gwid >> 7;             // 128 waves per image
    const int y0   = (gwid & 127) << 2;     // 4 rows per wave

    const float* Lp = logits  + (size_t)img * (H_ * W_) + (lane << 3);
    const float* Tp = targets + (size_t)img * (H_ * W_) + (lane << 3);

    // [0]=left halo, [1..8]=own cols, [9]=right halo
    float p0[10], p1[10], p2[10], p3[10], p4[10], p5[10];
    unsigned int w0, w1, w2, w3, w4, w5;

    auto loadrow = [&](int gy, float (&pr)[10], unsigned int& wr) {
        if ((unsigned)gy < (unsigned)H_) {   // wave-uniform branch: shuffles safe
            const float4 va = *(const float4*)(Lp + gy * W_);
            const float4 vb = *(const float4*)(Lp + gy * W_ + 4);
            const float4 vc = *(const float4*)(Tp + gy * W_);
            const float4 vd = *(const float4*)(Tp + gy * W_ + 4);
            pr[1] = sigf(va.x); pr[2] = sigf(va.y);
            pr[3] = sigf(va.z); pr[4] = sigf(va.w);
            pr[5] = sigf(vb.x); pr[6] = sigf(vb.y);
            pr[7] = sigf(vb.z); pr[8] = sigf(vb.w);
            unsigned int m =  (vc.x > 0.5f ? 1u : 0u)   | (vc.y > 0.5f ? 2u : 0u)
                           | (vc.z > 0.5f ? 4u : 0u)    | (vc.w > 0.5f ? 8u : 0u)
                           | (vd.x > 0.5f ? 16u : 0u)   | (vd.y > 0.5f ? 32u : 0u)
                           | (vd.z > 0.5f ? 64u : 0u)   | (vd.w > 0.5f ? 128u : 0u);
            float pl = __shfl_up(pr[8], 1, 64);
            float pr9 = __shfl_down(pr[1], 1, 64);
            unsigned int ml = __shfl_up(m, 1, 64);
            unsigned int mr = __shfl_down(m, 1, 64);
            if (lane == 0)  { pl = 0.f; ml = 0u; }
            if (lane == 63) { pr9 = 0.f; mr = 0u; }
            pr[0] = pl; pr[9] = pr9;
            wr = (m << 1) | ((ml >> 7) & 1u) | ((mr & 1u) << 9);
        } else {
            #pragma unroll
            for (int k = 0; k < 10; ++k) pr[k] = 0.f;
            wr = 0u;
        }
    };

    loadrow(y0 - 1, p0, w0);
    loadrow(y0,     p1, w1);
    loadrow(y0 + 1, p2, w2);
    loadrow(y0 + 2, p3, w3);
    loadrow(y0 + 3, p4, w4);
    loadrow(y0 + 4, p5, w5);

    float li = 0.f, lp = 0.f;
    int mi = 0;

    // One output row: prob rows (pa,pb,pc), mask rows (wa,wb,wc); pb/wb = center
    auto dorow = [&](const float (&pa)[10], const float (&pb)[10], const float (&pc)[10],
                     unsigned int wa, unsigned int wb, unsigned int wc) {
        float Tc[10], Sc[10];
        int tcol[10], scol[10];
        #pragma unroll
        for (int j = 0; j < 10; ++j) {
            Tc[j] = (pa[j] + pc[j]) + 2.f * pb[j];
            Sc[j] = pc[j] - pa[j];
            const int a = (int)((wa >> j) & 1u);
            const int b = (int)((wb >> j) & 1u);
            const int c = (int)((wc >> j) & 1u);
            tcol[j] = a + 2 * b + c;
            scol[j] = c - a;
        }
        #pragma unroll
        for (int k = 0; k < 8; ++k) {
            const float gx = Tc[k + 2] - Tc[k];
            const float gy = (Sc[k] + Sc[k + 2]) + 2.f * Sc[k + 1];
            const int pb_ = (gx * gx + gy * gy) > 0.25f;
            const int hx = tcol[k + 2] - tcol[k];
            const int hy = (scol[k] + scol[k + 2]) + 2 * scol[k + 1];
            const int tb = ((hx | hy) != 0) ? 1 : 0;   // exact integer Sobel
            mi += pb_ ^ tb;
            const float pv = pb[k + 1];
            lp += pv;
            if ((wb >> (k + 1)) & 1u) li += pv;
        }
    };

    dorow(p0, p1, p2, w0, w1, w2);
    dorow(p1, p2, p3, w1, w2, w3);
    dorow(p2, p3, p4, w2, w3, w4);
    dorow(p3, p4, p5, w3, w4, w5);

    float lt = (float)(__popc(w1 & 0x1FEu) + __popc(w2 & 0x1FEu) +
                       __popc(w3 & 0x1FEu) + __popc(w4 & 0x1FEu));
    float lm = (float)mi;

    #pragma unroll
    for (int off = 32; off > 0; off >>= 1) {
        li += __shfl_down(li, off, 64);
        lp += __shfl_down(lp, off, 64);
        lt += __shfl_down(lt, off, 64);
        lm += __shfl_down(lm, off, 64);
    }
    __shared__ float red[4][4];
    if (lane == 0) { red[wid][0] = li; red[wid][1] = lp; red[wid][2] = lt; red[wid][3] = lm; }
    __syncthreads();
    if (tid == 0) {
        float a = 0.f, b = 0.f, c = 0.f, d = 0.f;
        #pragma unroll
        for (int w = 0; w < 4; ++w) {
            a += red[w][0]; b += red[w][1]; c += red[w][2]; d += red[w][3];
        }
        part[bx] = make_float4(a, b, c, d);
    }
}

__global__ void finalize_kernel(const float4* __restrict__ part,
                                const float* __restrict__ cw,
                                float* __restrict__ out) {
    __shared__ float s_i[NIMG], s_p[NIMG], s_t[NIMG], s_m[NIMG];
    const int tid = threadIdx.x;           // 1024 threads, one per block-partial
    float4 v = part[tid];
    float vi = v.x, vp = v.y, vt = v.z, vm = v.w;
    #pragma unroll
    for (int off = 16; off > 0; off >>= 1) {   // 32 partials per image, segmented
        vi += __shfl_down(vi, off, 32);
        vp += __shfl_down(vp, off, 32);
        vt += __shfl_down(vt, off, 32);
        vm += __shfl_down(vm, off, 32);
    }
    if ((tid & 31) == 0) {
        const int img = tid >> 5;
        s_i[img] = vi; s_p[img] = vp; s_t[img] = vt; s_m[img] = vm;
    }
    __syncthreads();
    if (tid == 0) {
        float mm = 0.f;
        for (int i = 0; i < NIMG; ++i) mm += s_m[i];
        float wsum = 0.f, dl = 0.f;
        for (int c = 0; c < 4; ++c) {
            float md = 0.f;
            for (int b2 = 0; b2 < 8; ++b2) {
                const int id = b2 * 4 + c;
                md += (2.f * s_i[id] + 1.f) / (s_p[id] + s_t[id] + 1.f);
            }
            md *= 0.125f;
            dl += cw[c] * (1.f - md);
            wsum += cw[c];
        }
        out[0] = 0.7f * (dl / wsum) + 0.3f * (100.f * mm / NPIXF);
    }
}

extern "C" void kernel_launch(void* const* d_in, const int* in_sizes, int n_in,
                              void* d_out, int out_size, void* d_ws, size_t ws_size,
                              hipStream_t stream) {
    const float* logits  = (const float*)d_in[0];
    const float* targets = (const float*)d_in[1];
    const float* cw      = (const float*)d_in[2];
    float* out = (float*)d_out;
    float4* part = (float4*)d_ws;   // NBLK * 16 B = 16 KB

    fused_loss_kernel<<<NBLK, 256, 0, stream>>>(logits, targets, part);
    finalize_kernel<<<1, NBLK, 0, stream>>>(part, cw, out);
}

// Round 8
// 102.688 us; speedup vs baseline: 1.2718x; 1.0138x over previous
//
#include <hip/hip_runtime.h>

// CombinedLoss = 0.7 * class-weighted Dice + 0.3 * Sobel-boundary BCE
// [B=8,C=4,H=512,W=512] fp32. Binary boundary BCE == 100 * mismatch-rate.
// One wave = one 512-col strip (8 cols/lane), 4 output rows/wave, 6 input rows.
// Round-8 structure: ALL 24 float4 loads issued up front (branch-free via
// address clamp + post-hoc zeroing) for max memory-level parallelism; masks &
// sigmoids converted only afterwards. XCD swizzle (lbx = (bx&7)*128 + bx>>3)
// puts halo-sharing neighbor segments on the same XCD so re-reads hit its L2.
// Named row arrays with constant indices only (rotating windows spill - r5).

#define H_ 512
#define W_ 512
#define NIMG 32
#define NPIXF 8388608.0f
#define NBLK 1024   // 4096 waves = 32 img * 128 segs(4 rows) / 4 waves-per-block

__device__ __forceinline__ float sigf(float x) {
    return __builtin_amdgcn_rcpf(1.f + __expf(-x));
}

__launch_bounds__(256)
__global__ void fused_loss_kernel(const float* __restrict__ logits,
                                  const float* __restrict__ targets,
                                  float4* __restrict__ part) {
    const int tid  = threadIdx.x;
    const int wid  = tid >> 6, lane = tid & 63;
    const int bx   = blockIdx.x;
    const int lbx  = ((bx & 7) << 7) | (bx >> 3);   // XCD-grouping swizzle
    const int gwid = (lbx << 2) | wid;              // 0..4095
    const int img  = gwid >> 7;                     // 128 segments per image
    const int y0   = (gwid & 127) << 2;             // 4 rows per segment

    const size_t base = (size_t)img * (H_ * W_) + (lane << 3);
    const float* L = logits + base;
    const float* T = targets + base;

    const int o0 = ((y0 > 0) ? (y0 - 1) : 0) * W_;          // clamped; zeroed later
    const int o1 = y0 * W_;
    const int o2 = o1 + W_;
    const int o3 = o2 + W_;
    const int o4 = o3 + W_;
    const int o5 = ((y0 < H_ - 4) ? (y0 + 4) : (H_ - 1)) * W_;

    // ---- phase 1: 12 target loads (no consumption in between) ----
    const float4 ta0 = *(const float4*)(T + o0), tb0 = *(const float4*)(T + o0 + 4);
    const float4 ta1 = *(const float4*)(T + o1), tb1 = *(const float4*)(T + o1 + 4);
    const float4 ta2 = *(const float4*)(T + o2), tb2 = *(const float4*)(T + o2 + 4);
    const float4 ta3 = *(const float4*)(T + o3), tb3 = *(const float4*)(T + o3 + 4);
    const float4 ta4 = *(const float4*)(T + o4), tb4 = *(const float4*)(T + o4 + 4);
    const float4 ta5 = *(const float4*)(T + o5), tb5 = *(const float4*)(T + o5 + 4);
    // ---- phase 2: 12 logit loads ----
    const float4 la0 = *(const float4*)(L + o0), lb0 = *(const float4*)(L + o0 + 4);
    const float4 la1 = *(const float4*)(L + o1), lb1 = *(const float4*)(L + o1 + 4);
    const float4 la2 = *(const float4*)(L + o2), lb2 = *(const float4*)(L + o2 + 4);
    const float4 la3 = *(const float4*)(L + o3), lb3 = *(const float4*)(L + o3 + 4);
    const float4 la4 = *(const float4*)(L + o4), lb4 = *(const float4*)(L + o4 + 4);
    const float4 la5 = *(const float4*)(L + o5), lb5 = *(const float4*)(L + o5 + 4);

    // ---- phase 3: masks from targets (frees target regs) ----
    auto mk = [](const float4& a, const float4& b) -> unsigned int {
        return (a.x > 0.5f ? 1u : 0u)   | (a.y > 0.5f ? 2u : 0u)
             | (a.z > 0.5f ? 4u : 0u)   | (a.w > 0.5f ? 8u : 0u)
             | (b.x > 0.5f ? 16u : 0u)  | (b.y > 0.5f ? 32u : 0u)
             | (b.z > 0.5f ? 64u : 0u)  | (b.w > 0.5f ? 128u : 0u);
    };
    unsigned int m0 = mk(ta0, tb0), m1 = mk(ta1, tb1), m2 = mk(ta2, tb2);
    unsigned int m3 = mk(ta3, tb3), m4 = mk(ta4, tb4), m5 = mk(ta5, tb5);
    if (y0 == 0)       m0 = 0u;     // wave-uniform
    if (y0 == H_ - 4)  m5 = 0u;

    // mask halos: pack bit7s / bit0s of all 6 rows -> 2 shuffles total
    unsigned int hi = ((m0 >> 7) & 1u)        | (((m1 >> 7) & 1u) << 1)
                    | (((m2 >> 7) & 1u) << 2) | (((m3 >> 7) & 1u) << 3)
                    | (((m4 >> 7) & 1u) << 4) | (((m5 >> 7) & 1u) << 5);
    unsigned int lo = (m0 & 1u)        | ((m1 & 1u) << 1) | ((m2 & 1u) << 2)
                    | ((m3 & 1u) << 3) | ((m4 & 1u) << 4) | ((m5 & 1u) << 5);
    unsigned int hin = __shfl_up(hi, 1, 64);    // lane-1's rightmost cols
    unsigned int lon = __shfl_down(lo, 1, 64);  // lane+1's leftmost cols
    if (lane == 0)  hin = 0u;
    if (lane == 63) lon = 0u;
    const unsigned int w0 = (m0 << 1) | ( hin       & 1u) | (( lon       & 1u) << 9);
    const unsigned int w1 = (m1 << 1) | ((hin >> 1) & 1u) | (((lon >> 1) & 1u) << 9);
    const unsigned int w2 = (m2 << 1) | ((hin >> 2) & 1u) | (((lon >> 2) & 1u) << 9);
    const unsigned int w3 = (m3 << 1) | ((hin >> 3) & 1u) | (((lon >> 3) & 1u) << 9);
    const unsigned int w4 = (m4 << 1) | ((hin >> 4) & 1u) | (((lon >> 4) & 1u) << 9);
    const unsigned int w5 = (m5 << 1) | ((hin >> 5) & 1u) | (((lon >> 5) & 1u) << 9);

    // ---- phase 4: sigmoids + prob halos ----
    float p0[10], p1[10], p2[10], p3[10], p4[10], p5[10];
    auto cvt = [&](const float4& a, const float4& b, float (&pr)[10], bool zero) {
        if (zero) {                       // wave-uniform
            #pragma unroll
            for (int k = 1; k <= 8; ++k) pr[k] = 0.f;
        } else {
            pr[1] = sigf(a.x); pr[2] = sigf(a.y); pr[3] = sigf(a.z); pr[4] = sigf(a.w);
            pr[5] = sigf(b.x); pr[6] = sigf(b.y); pr[7] = sigf(b.z); pr[8] = sigf(b.w);
        }
        float pl = __shfl_up(pr[8], 1, 64);
        float pr9 = __shfl_down(pr[1], 1, 64);
        if (lane == 0)  pl = 0.f;
        if (lane == 63) pr9 = 0.f;
        pr[0] = pl; pr[9] = pr9;
    };
    cvt(la0, lb0, p0, y0 == 0);
    cvt(la1, lb1, p1, false);
    cvt(la2, lb2, p2, false);
    cvt(la3, lb3, p3, false);
    cvt(la4, lb4, p4, false);
    cvt(la5, lb5, p5, y0 == H_ - 4);

    float li = 0.f, lp = 0.f;
    int mi = 0;

    // One output row: prob rows (pa,pb,pc), mask rows (wa,wb,wc); pb/wb = center
    auto dorow = [&](const float (&pa)[10], const float (&pb)[10], const float (&pc)[10],
                     unsigned int wa, unsigned int wb, unsigned int wc) {
        float Tc[10], Sc[10];
        int tcol[10], scol[10];
        #pragma unroll
        for (int j = 0; j < 10; ++j) {
            Tc[j] = (pa[j] + pc[j]) + 2.f * pb[j];
            Sc[j] = pc[j] - pa[j];
            const int a = (int)((wa >> j) & 1u);
            const int b = (int)((wb >> j) & 1u);
            const int c = (int)((wc >> j) & 1u);
            tcol[j] = a + 2 * b + c;
            scol[j] = c - a;
        }
        #pragma unroll
        for (int k = 0; k < 8; ++k) {
            const float gx = Tc[k + 2] - Tc[k];
            const float gy = (Sc[k] + Sc[k + 2]) + 2.f * Sc[k + 1];
            const int pb_ = (gx * gx + gy * gy) > 0.25f;
            const int hx = tcol[k + 2] - tcol[k];
            const int hy = (scol[k] + scol[k + 2]) + 2 * scol[k + 1];
            const int tb = ((hx | hy) != 0) ? 1 : 0;   // exact integer Sobel
            mi += pb_ ^ tb;
            const float pv = pb[k + 1];
            lp += pv;
            if ((wb >> (k + 1)) & 1u) li += pv;
        }
    };

    dorow(p0, p1, p2, w0, w1, w2);
    dorow(p1, p2, p3, w1, w2, w3);
    dorow(p2, p3, p4, w2, w3, w4);
    dorow(p3, p4, p5, w3, w4, w5);

    float lt = (float)(__popc(w1 & 0x1FEu) + __popc(w2 & 0x1FEu) +
                       __popc(w3 & 0x1FEu) + __popc(w4 & 0x1FEu));
    float lm = (float)mi;

    #pragma unroll
    for (int off = 32; off > 0; off >>= 1) {
        li += __shfl_down(li, off, 64);
        lp += __shfl_down(lp, off, 64);
        lt += __shfl_down(lt, off, 64);
        lm += __shfl_down(lm, off, 64);
    }
    __shared__ float red[4][4];
    if (lane == 0) { red[wid][0] = li; red[wid][1] = lp; red[wid][2] = lt; red[wid][3] = lm; }
    __syncthreads();
    if (tid == 0) {
        float a = 0.f, b = 0.f, c = 0.f, d = 0.f;
        #pragma unroll
        for (int w = 0; w < 4; ++w) {
            a += red[w][0]; b += red[w][1]; c += red[w][2]; d += red[w][3];
        }
        part[lbx] = make_float4(a, b, c, d);   // lbx: partials grouped by image
    }
}

__global__ void finalize_kernel(const float4* __restrict__ part,
                                const float* __restrict__ cw,
                                float* __restrict__ out) {
    __shared__ float s_i[NIMG], s_p[NIMG], s_t[NIMG], s_m[NIMG];
    const int tid = threadIdx.x;           // 1024 threads, one per block-partial
    float4 v = part[tid];
    float vi = v.x, vp = v.y, vt = v.z, vm = v.w;
    #pragma unroll
    for (int off = 16; off > 0; off >>= 1) {   // 32 partials per image, segmented
        vi += __shfl_down(vi, off, 32);
        vp += __shfl_down(vp, off, 32);
        vt += __shfl_down(vt, off, 32);
        vm += __shfl_down(vm, off, 32);
    }
    if ((tid & 31) == 0) {
        const int img = tid >> 5;
        s_i[img] = vi; s_p[img] = vp; s_t[img] = vt; s_m[img] = vm;
    }
    __syncthreads();
    if (tid == 0) {
        float mm = 0.f;
        for (int i = 0; i < NIMG; ++i) mm += s_m[i];
        float wsum = 0.f, dl = 0.f;
        for (int c = 0; c < 4; ++c) {
            float md = 0.f;
            for (int b2 = 0; b2 < 8; ++b2) {
                const int id = b2 * 4 + c;
                md += (2.f * s_i[id] + 1.f) / (s_p[id] + s_t[id] + 1.f);
            }
            md *= 0.125f;
            dl += cw[c] * (1.f - md);
            wsum += cw[c];
        }
        out[0] = 0.7f * (dl / wsum) + 0.3f * (100.f * mm / NPIXF);
    }
}

extern "C" void kernel_launch(void* const* d_in, const int* in_sizes, int n_in,
                              void* d_out, int out_size, void* d_ws, size_t ws_size,
                              hipStream_t stream) {
    const float* logits  = (const float*)d_in[0];
    const float* targets = (const float*)d_in[1];
    const float* cw      = (const float*)d_in[2];
    float* out = (float*)d_out;
    float4* part = (float4*)d_ws;   // NBLK * 16 B = 16 KB

    fused_loss_kernel<<<NBLK, 256, 0, stream>>>(logits, targets, part);
    finalize_kernel<<<1, NBLK, 0, stream>>>(part, cw, out);
}